// Round 6
// baseline (291.708 us; speedup 1.0000x reference)
//
#include <hip/hip_runtime.h>
#include <hip/hip_fp16.h>
#include <stdint.h>

#define H_   256
#define W_   256
#define HW_  65536
#define NIMG 8

#define TI   16
#define TJ   64
#define HALO 10
#define RDI  36   // TI + 2*HALO
#define RDJ  84   // TJ + 2*HALO

typedef _Float16 half8_t __attribute__((ext_vector_type(8)));
typedef __fp16   fp16x2  __attribute__((ext_vector_type(2)));
typedef float    float4_t __attribute__((ext_vector_type(4)));

__device__ __forceinline__ uint32_t pk2(float a, float b) {
    fp16x2 h = __builtin_amdgcn_cvt_pkrtz(a, b);
    union { fp16x2 h; uint32_t u; } v; v.h = h; return v.u;
}
__device__ __forceinline__ __half2 u2h(uint32_t u) {
    union { uint32_t u; __half2 h; } v; v.u = u; return v.h;
}
__device__ __forceinline__ __half2 lerp2(__half2 p, __half2 q, __half2 f) {
    return __hfma2(f, __hsub2(q, p), p);
}

// ---------------- Kernel A: pointwise conv via MFMA f16, LDS-staged x ----------------
// (frozen: resisted 3 structural interventions at ~64us pinned)
__global__ __launch_bounds__(256) void pw_off_kernel(
    const float* __restrict__ x, const float* __restrict__ pw,
    const float* __restrict__ offw, const float* __restrict__ offb,
    uint32_t* __restrict__ ypackI, float* __restrict__ sbuf)
{
    __shared__ uint32_t xs2[32][260];   // 32.5 KB: [channel-pair][pixel] packed half2

    const int t    = threadIdx.x;
    const int blk  = blockIdx.x;          // 2048 blocks, 256 px each
    const int n    = blk >> 8;
    const int hw0  = (blk & 255) << 8;
    const int lane = t & 63;
    const int l15  = lane & 15;
    const int q    = lane >> 4;
    const int wv   = t >> 6;

    half8_t af[4][2];
    #pragma unroll
    for (int mt = 0; mt < 4; ++mt) {
        #pragma unroll
        for (int kt = 0; kt < 2; ++kt) {
            const float* wr = pw + (mt * 16 + l15) * 64 + kt * 32 + q * 8;
            float4 w0 = *(const float4*)wr;
            float4 w1 = *(const float4*)(wr + 4);
            union { uint32_t u[4]; half8_t h; } v;
            v.u[0] = pk2(w0.x, w0.y); v.u[1] = pk2(w0.z, w0.w);
            v.u[2] = pk2(w1.x, w1.y); v.u[3] = pk2(w1.z, w1.w);
            af[mt][kt] = v.h;
        }
    }
    float4_t ow4[4];
    #pragma unroll
    for (int mt = 0; mt < 4; ++mt)
        ow4[mt] = *(const float4_t*)(offw + mt * 16 + q * 4);
    const float bias = offb[0];

    const float* xb = x + (size_t)n * 64 * HW_ + hw0 + lane * 4;
    #pragma unroll
    for (int g = 0; g < 2; ++g) {
        float4 va[4], vb[4];
        #pragma unroll
        for (int u = 0; u < 4; ++u) {
            const int c2 = (g * 4 + u) * 4 + wv;
            va[u] = *(const float4*)(xb + (size_t)(2 * c2) * HW_);
            vb[u] = *(const float4*)(xb + (size_t)(2 * c2 + 1) * HW_);
        }
        #pragma unroll
        for (int u = 0; u < 4; ++u) {
            const int c2 = (g * 4 + u) * 4 + wv;
            uint4 w;
            w.x = pk2(va[u].x, vb[u].x);
            w.y = pk2(va[u].y, vb[u].y);
            w.z = pk2(va[u].z, vb[u].z);
            w.w = pk2(va[u].w, vb[u].w);
            *(uint4*)&xs2[c2][lane * 4] = w;
        }
    }
    __syncthreads();

    #pragma unroll
    for (int j = 0; j < 4; ++j) {
        const int pix = (wv * 4 + j) * 16 + l15;
        const int hw  = hw0 + pix;

        half8_t bf[2];
        #pragma unroll
        for (int kt = 0; kt < 2; ++kt) {
            union { uint32_t u[4]; half8_t h; } vv;
            #pragma unroll
            for (int cc = 0; cc < 4; ++cc)
                vv.u[cc] = xs2[kt * 16 + q * 4 + cc][pix];
            bf[kt] = vv.h;
        }

        float4_t acc[4] = {{0,0,0,0},{0,0,0,0},{0,0,0,0},{0,0,0,0}};
        #pragma unroll
        for (int kt = 0; kt < 2; ++kt) {
            #pragma unroll
            for (int mt = 0; mt < 4; ++mt)
                acc[mt] = __builtin_amdgcn_mfma_f32_16x16x32_f16(af[mt][kt], bf[kt], acc[mt], 0, 0, 0);
        }

        float sp = 0.f;
        #pragma unroll
        for (int mt = 0; mt < 4; ++mt)
            sp += acc[mt][0] * ow4[mt][0] + acc[mt][1] * ow4[mt][1]
                + acc[mt][2] * ow4[mt][2] + acc[mt][3] * ow4[mt][3];
        sp += __shfl_xor(sp, 16, 64);
        sp += __shfl_xor(sp, 32, 64);
        float sv = fminf(fmaxf(sp + bias, 0.f), 8.f);
        if (q == 0) sbuf[(size_t)n * HW_ + hw] = sv;

        #pragma unroll
        for (int mt = 0; mt < 4; ++mt) {
            uint2 st;
            st.x = pk2(acc[mt][0], acc[mt][1]);
            st.y = pk2(acc[mt][2], acc[mt][3]);
            const int pg = mt * 2 + (q >> 1);
            size_t ad = (((size_t)(n * 8 + pg)) * HW_ + hw) * 4 + (q & 1) * 2;
            *(uint2*)&ypackI[ad] = st;
        }
    }
}

// ---------------- Kernel B: deformable depthwise 3x3, separable bilinear ----------------
// v5: occupancy experiment — exact R1 body, tile 32x64 -> 16x64 (smem 48.4KB -> 3
// blocks/CU), 512 thr, qq-loop 2, __launch_bounds__(512,6) caps VGPR at 85 so all
// 3 blocks (24 waves/CU = 6/SIMD, +50%) become resident. Rolled staging (split-phase
// measured null in R3) keeps registers under the cap.
__global__ __launch_bounds__(512, 6) void deform_kernel(
    const uint4* __restrict__ ypackI, const float* __restrict__ sbuf,
    const float* __restrict__ dwp, float* __restrict__ out)
{
    __shared__ uint4 smem[RDI * RDJ];   // 48.4 KB -> 3 blocks/CU

    const int t  = threadIdx.x;
    const int tj = blockIdx.x;   // 0..3
    const int ti = blockIdx.y;   // 0..15
    const int z  = blockIdx.z;   // n*8 + pg
    const int n  = z >> 3;
    const int pg = z & 7;
    const int i0 = ti * TI, j0 = tj * TJ;

    // ---- stage zero-padded interleaved region (rolled) ----
    const size_t ybase = (size_t)z * HW_;
    for (int idx = t; idx < RDI * RDJ; idx += 512) {
        int r  = idx / RDJ;
        int c  = idx - r * RDJ;
        int gr = i0 - HALO + r;
        int gc = j0 - HALO + c;
        bool ok = (gr >= 0) & (gr < H_) & (gc >= 0) & (gc < W_);
        uint4 v = {0u, 0u, 0u, 0u};
        if (ok) v = ypackI[ybase + gr * W_ + gc];
        smem[idx] = v;
    }

    // depthwise weights (uniform scalar loads), packed per channel-pair
    const int c0 = pg * 8;
    __half2 d2[4][9];
    #pragma unroll
    for (int pp = 0; pp < 4; ++pp) {
        #pragma unroll
        for (int k = 0; k < 9; ++k)
            d2[pp][k] = __floats2half2_rn(dwp[(c0 + 2 * pp) * 9 + k],
                                          dwp[(c0 + 2 * pp + 1) * 9 + k]);
    }

    const int lj = t & 63;      // column within tile 0..63
    const int l8 = t >> 6;      // wave row 0..7

    // prefetch offset scalars (latency hides under barrier wait)
    float sv2[2];
    #pragma unroll
    for (int qq = 0; qq < 2; ++qq)
        sv2[qq] = sbuf[(size_t)n * HW_ + (i0 + l8 + qq * 8) * W_ + (j0 + lj)];

    __syncthreads();

    #pragma unroll
    for (int qq = 0; qq < 2; ++qq) {
        const int li = l8 + qq * 8;           // 0..15
        const int gi = i0 + li, gj = j0 + lj;
        const float sv = sv2[qq];
        const float tt = 1.0f + sv;
        const float lr = (float)(li + HALO);
        const float lc = (float)(lj + HALO);
        const int ra0 = (int)floorf(lr - tt); const float fya = (lr - tt) - (float)ra0;
        const int rb0 = (int)floorf(lr + tt); const float fyb = (lr + tt) - (float)rb0;
        const int ca0 = (int)floorf(lc - tt); const float fxa = (lc - tt) - (float)ca0;
        const int cb0 = (int)floorf(lc + tt); const float fxb = (lc + tt) - (float)cb0;
        const int rc = li + HALO, cc = lj + HALO;
        const __half2 fxa2 = __float2half2_rn(fxa);
        const __half2 fxb2 = __float2half2_rn(fxb);
        const __half2 fya2 = __float2half2_rn(fya);
        const __half2 fyb2 = __float2half2_rn(fyb);

        __half2 A0[4], C0[4], B0[4], A1[4], C1[4], B1[4];

#define LOADCOLS(ro, Av, Cv, Bv) do {                                   \
        uint4 v0 = smem[(ro) + ca0]; uint4 v1 = smem[(ro) + ca0 + 1];   \
        uint4 vc = smem[(ro) + cc];                                     \
        uint4 v3 = smem[(ro) + cb0]; uint4 v4 = smem[(ro) + cb0 + 1];   \
        const uint32_t* p0 = (const uint32_t*)&v0;                      \
        const uint32_t* p1 = (const uint32_t*)&v1;                      \
        const uint32_t* pc = (const uint32_t*)&vc;                      \
        const uint32_t* p3 = (const uint32_t*)&v3;                      \
        const uint32_t* p4 = (const uint32_t*)&v4;                      \
        _Pragma("unroll")                                               \
        for (int pp = 0; pp < 4; ++pp) {                                \
            Av[pp] = lerp2(u2h(p0[pp]), u2h(p1[pp]), fxa2);             \
            Cv[pp] = u2h(pc[pp]);                                       \
            Bv[pp] = lerp2(u2h(p3[pp]), u2h(p4[pp]), fxb2);             \
        } } while (0)

        __half2 acc[4];
        // ky = 0 : rows ra0, ra0+1 lerped by fya
        LOADCOLS(ra0 * RDJ, A0, C0, B0);
        LOADCOLS((ra0 + 1) * RDJ, A1, C1, B1);
        #pragma unroll
        for (int pp = 0; pp < 4; ++pp) {
            __half2 SA = lerp2(A0[pp], A1[pp], fya2);
            __half2 SC = lerp2(C0[pp], C1[pp], fya2);
            __half2 SB = lerp2(B0[pp], B1[pp], fya2);
            acc[pp] = __hmul2(d2[pp][0], SA);
            acc[pp] = __hfma2(d2[pp][1], SC, acc[pp]);
            acc[pp] = __hfma2(d2[pp][2], SB, acc[pp]);
        }
        // ky = 1 : exact center row
        LOADCOLS(rc * RDJ, A0, C0, B0);
        #pragma unroll
        for (int pp = 0; pp < 4; ++pp) {
            acc[pp] = __hfma2(d2[pp][3], A0[pp], acc[pp]);
            acc[pp] = __hfma2(d2[pp][4], C0[pp], acc[pp]);
            acc[pp] = __hfma2(d2[pp][5], B0[pp], acc[pp]);
        }
        // ky = 2 : rows rb0, rb0+1 lerped by fyb
        LOADCOLS(rb0 * RDJ, A0, C0, B0);
        LOADCOLS((rb0 + 1) * RDJ, A1, C1, B1);
        #pragma unroll
        for (int pp = 0; pp < 4; ++pp) {
            __half2 SA = lerp2(A0[pp], A1[pp], fyb2);
            __half2 SC = lerp2(C0[pp], C1[pp], fyb2);
            __half2 SB = lerp2(B0[pp], B1[pp], fyb2);
            acc[pp] = __hfma2(d2[pp][6], SA, acc[pp]);
            acc[pp] = __hfma2(d2[pp][7], SC, acc[pp]);
            acc[pp] = __hfma2(d2[pp][8], SB, acc[pp]);
        }
#undef LOADCOLS

        const size_t ob = ((size_t)n * 64 + c0) * HW_ + gi * W_ + gj;
        #pragma unroll
        for (int pp = 0; pp < 4; ++pp) {
            out[ob + (size_t)(2 * pp) * HW_]     = __low2float(acc[pp]);
            out[ob + (size_t)(2 * pp + 1) * HW_] = __high2float(acc[pp]);
        }
    }
}

extern "C" void kernel_launch(void* const* d_in, const int* in_sizes, int n_in,
                              void* d_out, int out_size, void* d_ws, size_t ws_size,
                              hipStream_t stream) {
    const float* x    = (const float*)d_in[0];
    const float* pw   = (const float*)d_in[1];
    const float* offw = (const float*)d_in[2];
    const float* offb = (const float*)d_in[3];
    const float* dwp  = (const float*)d_in[4];

    uint32_t* ypackI = (uint32_t*)d_ws;                                 // 64 MiB
    float* sbuf = (float*)((char*)d_ws + (size_t)NIMG * 8 * HW_ * 16);  // 2 MiB
    float* out  = (float*)d_out;

    hipLaunchKernelGGL(pw_off_kernel, dim3(2048), dim3(256), 0, stream,
                       x, pw, offw, offb, ypackI, sbuf);
    hipLaunchKernelGGL(deform_kernel, dim3(4, 16, NIMG * 8), dim3(512), 0, stream,
                       (const uint4*)ypackI, sbuf, dwp, out);
}

// Round 11
// 285.074 us; speedup vs baseline: 1.0233x; 1.0233x over previous
//
#include <hip/hip_runtime.h>
#include <hip/hip_fp16.h>
#include <stdint.h>

#define H_   256
#define W_   256
#define HW_  65536
#define NIMG 8

#define TI   32
#define TJ   64
#define HALO 10
#define RDI  52   // TI + 2*HALO
#define RDJ  84   // TJ + 2*HALO

typedef _Float16 half8_t __attribute__((ext_vector_type(8)));
typedef __fp16   fp16x2  __attribute__((ext_vector_type(2)));
typedef float    float4_t __attribute__((ext_vector_type(4)));

__device__ __forceinline__ uint32_t pk2(float a, float b) {
    fp16x2 h = __builtin_amdgcn_cvt_pkrtz(a, b);
    union { fp16x2 h; uint32_t u; } v; v.h = h; return v.u;
}
__device__ __forceinline__ __half2 u2h(uint32_t u) {
    union { uint32_t u; __half2 h; } v; v.u = u; return v.h;
}
__device__ __forceinline__ __half2 lerp2(__half2 p, __half2 q, __half2 f) {
    return __hfma2(f, __hsub2(q, p), p);
}

// ---------------- Kernel A: pointwise conv via MFMA f16 (R3 best-measured) ----------------
// 2-deep software-pipelined x loads.
__global__ __launch_bounds__(256) void pw_off_kernel(
    const float* __restrict__ x, const float* __restrict__ pw,
    const float* __restrict__ offw, const float* __restrict__ offb,
    uint32_t* __restrict__ ypackI, float* __restrict__ sbuf)
{
    const int t    = threadIdx.x;
    const int blk  = blockIdx.x;          // 2048 blocks, 256 px each
    const int n    = blk >> 8;
    const int hw0  = (blk & 255) << 8;
    const int lane = t & 63;
    const int l15  = lane & 15;
    const int q    = lane >> 4;
    const int wv   = t >> 6;

    half8_t af[4][2];
    #pragma unroll
    for (int mt = 0; mt < 4; ++mt) {
        #pragma unroll
        for (int kt = 0; kt < 2; ++kt) {
            const float* wr = pw + (mt * 16 + l15) * 64 + kt * 32 + q * 8;
            float4 w0 = *(const float4*)wr;
            float4 w1 = *(const float4*)(wr + 4);
            union { uint32_t u[4]; half8_t h; } v;
            v.u[0] = pk2(w0.x, w0.y); v.u[1] = pk2(w0.z, w0.w);
            v.u[2] = pk2(w1.x, w1.y); v.u[3] = pk2(w1.z, w1.w);
            af[mt][kt] = v.h;
        }
    }
    float4_t ow4[4];
    #pragma unroll
    for (int mt = 0; mt < 4; ++mt)
        ow4[mt] = *(const float4_t*)(offw + mt * 16 + q * 4);
    const float bias = offb[0];

    const float* xbase = x + (size_t)n * 64 * HW_;

    float rv[2][16];
#define ISSUE(jj, buf) do {                                              \
        const int pix_ = (wv * 4 + (jj)) * 16 + l15;                     \
        const float* xp_ = xbase + hw0 + pix_;                           \
        _Pragma("unroll")                                                \
        for (int kt_ = 0; kt_ < 2; ++kt_) {                              \
            const float* xk_ = xp_ + (size_t)(kt_ * 32 + q * 8) * HW_;   \
            _Pragma("unroll")                                            \
            for (int c_ = 0; c_ < 8; ++c_)                               \
                rv[buf][kt_ * 8 + c_] = xk_[(size_t)c_ * HW_];           \
        } } while (0)

    ISSUE(0, 0);

    #pragma unroll
    for (int j = 0; j < 4; ++j) {
        if (j < 3) ISSUE(j + 1, (j + 1) & 1);   // prefetch next pixel-group

        const int jb  = j & 1;
        const int pix = (wv * 4 + j) * 16 + l15;
        const int hw  = hw0 + pix;

        half8_t bf[2];
        #pragma unroll
        for (int kt = 0; kt < 2; ++kt) {
            union { uint32_t u[4]; half8_t h; } vv;
            vv.u[0] = pk2(rv[jb][kt * 8 + 0], rv[jb][kt * 8 + 1]);
            vv.u[1] = pk2(rv[jb][kt * 8 + 2], rv[jb][kt * 8 + 3]);
            vv.u[2] = pk2(rv[jb][kt * 8 + 4], rv[jb][kt * 8 + 5]);
            vv.u[3] = pk2(rv[jb][kt * 8 + 6], rv[jb][kt * 8 + 7]);
            bf[kt] = vv.h;
        }

        float4_t acc[4] = {{0,0,0,0},{0,0,0,0},{0,0,0,0},{0,0,0,0}};
        #pragma unroll
        for (int kt = 0; kt < 2; ++kt) {
            #pragma unroll
            for (int mt = 0; mt < 4; ++mt)
                acc[mt] = __builtin_amdgcn_mfma_f32_16x16x32_f16(af[mt][kt], bf[kt], acc[mt], 0, 0, 0);
        }

        float sp = 0.f;
        #pragma unroll
        for (int mt = 0; mt < 4; ++mt)
            sp += acc[mt][0] * ow4[mt][0] + acc[mt][1] * ow4[mt][1]
                + acc[mt][2] * ow4[mt][2] + acc[mt][3] * ow4[mt][3];
        sp += __shfl_xor(sp, 16, 64);
        sp += __shfl_xor(sp, 32, 64);
        float sv = fminf(fmaxf(sp + bias, 0.f), 8.f);
        if (q == 0) sbuf[(size_t)n * HW_ + hw] = sv;

        #pragma unroll
        for (int mt = 0; mt < 4; ++mt) {
            uint2 st;
            st.x = pk2(acc[mt][0], acc[mt][1]);
            st.y = pk2(acc[mt][2], acc[mt][3]);
            const int pg = mt * 2 + (q >> 1);
            size_t ad = (((size_t)(n * 8 + pg)) * HW_ + hw) * 4 + (q & 1) * 2;
            *(uint2*)&ypackI[ad] = st;
        }
    }
#undef ISSUE
}

// ---------------- Kernel B: deformable depthwise 3x3, separable bilinear ----------------
// Exact R1 version (measured fastest): 32x64 tile, 512 threads, split-phase staging.
__global__ __launch_bounds__(512) void deform_kernel(
    const uint4* __restrict__ ypackI, const float* __restrict__ sbuf,
    const float* __restrict__ dwp, float* __restrict__ out)
{
    __shared__ uint4 smem[RDI * RDJ];   // 69.9 KB -> 2 blocks/CU

    const int t  = threadIdx.x;
    const int tj = blockIdx.x;   // 0..3
    const int ti = blockIdx.y;   // 0..7
    const int z  = blockIdx.z;   // n*8 + pg
    const int n  = z >> 3;
    const int pg = z & 7;
    const int i0 = ti * TI, j0 = tj * TJ;

    // ---- stage zero-padded interleaved region: issue-early / write-late ----
    const size_t ybase = (size_t)z * HW_;
    uint4 vst[9];
    #pragma unroll
    for (int u = 0; u < 9; ++u) {
        const int idx = t + u * 512;
        uint4 v = {0u, 0u, 0u, 0u};
        if (u < 8 || t < RDI * RDJ - 8 * 512) {     // 4368 total
            int r  = idx / RDJ;
            int c  = idx - r * RDJ;
            int gr = i0 - HALO + r;
            int gc = j0 - HALO + c;
            bool ok = (gr >= 0) & (gr < H_) & (gc >= 0) & (gc < W_);
            if (ok) v = ypackI[ybase + gr * W_ + gc];
        }
        vst[u] = v;
    }
    #pragma unroll
    for (int u = 0; u < 9; ++u) {
        const int idx = t + u * 512;
        if (u < 8 || t < RDI * RDJ - 8 * 512)
            smem[idx] = vst[u];
    }

    // depthwise weights (uniform scalar loads), packed per channel-pair
    const int c0 = pg * 8;
    __half2 d2[4][9];
    #pragma unroll
    for (int pp = 0; pp < 4; ++pp) {
        #pragma unroll
        for (int k = 0; k < 9; ++k)
            d2[pp][k] = __floats2half2_rn(dwp[(c0 + 2 * pp) * 9 + k],
                                          dwp[(c0 + 2 * pp + 1) * 9 + k]);
    }
    __syncthreads();

    const int lj = t & 63;      // column within tile 0..63
    const int l8 = t >> 6;      // wave row 0..7

    #pragma unroll
    for (int qq = 0; qq < 4; ++qq) {
        const int li = l8 + qq * 8;           // 0..31
        const int gi = i0 + li, gj = j0 + lj;
        const float sv = sbuf[(size_t)n * HW_ + gi * W_ + gj];
        const float tt = 1.0f + sv;
        const float lr = (float)(li + HALO);
        const float lc = (float)(lj + HALO);
        const int ra0 = (int)floorf(lr - tt); const float fya = (lr - tt) - (float)ra0;
        const int rb0 = (int)floorf(lr + tt); const float fyb = (lr + tt) - (float)rb0;
        const int ca0 = (int)floorf(lc - tt); const float fxa = (lc - tt) - (float)ca0;
        const int cb0 = (int)floorf(lc + tt); const float fxb = (lc + tt) - (float)cb0;
        const int rc = li + HALO, cc = lj + HALO;
        const __half2 fxa2 = __float2half2_rn(fxa);
        const __half2 fxb2 = __float2half2_rn(fxb);
        const __half2 fya2 = __float2half2_rn(fya);
        const __half2 fyb2 = __float2half2_rn(fyb);

        __half2 A0[4], C0[4], B0[4], A1[4], C1[4], B1[4];

#define LOADCOLS(ro, Av, Cv, Bv) do {                                   \
        uint4 v0 = smem[(ro) + ca0]; uint4 v1 = smem[(ro) + ca0 + 1];   \
        uint4 vc = smem[(ro) + cc];                                     \
        uint4 v3 = smem[(ro) + cb0]; uint4 v4 = smem[(ro) + cb0 + 1];   \
        const uint32_t* p0 = (const uint32_t*)&v0;                      \
        const uint32_t* p1 = (const uint32_t*)&v1;                      \
        const uint32_t* pc = (const uint32_t*)&vc;                      \
        const uint32_t* p3 = (const uint32_t*)&v3;                      \
        const uint32_t* p4 = (const uint32_t*)&v4;                      \
        _Pragma("unroll")                                               \
        for (int pp = 0; pp < 4; ++pp) {                                \
            Av[pp] = lerp2(u2h(p0[pp]), u2h(p1[pp]), fxa2);             \
            Cv[pp] = u2h(pc[pp]);                                       \
            Bv[pp] = lerp2(u2h(p3[pp]), u2h(p4[pp]), fxb2);             \
        } } while (0)

        __half2 acc[4];
        // ky = 0 : rows ra0, ra0+1 lerped by fya
        LOADCOLS(ra0 * RDJ, A0, C0, B0);
        LOADCOLS((ra0 + 1) * RDJ, A1, C1, B1);
        #pragma unroll
        for (int pp = 0; pp < 4; ++pp) {
            __half2 SA = lerp2(A0[pp], A1[pp], fya2);
            __half2 SC = lerp2(C0[pp], C1[pp], fya2);
            __half2 SB = lerp2(B0[pp], B1[pp], fya2);
            acc[pp] = __hmul2(d2[pp][0], SA);
            acc[pp] = __hfma2(d2[pp][1], SC, acc[pp]);
            acc[pp] = __hfma2(d2[pp][2], SB, acc[pp]);
        }
        // ky = 1 : exact center row
        LOADCOLS(rc * RDJ, A0, C0, B0);
        #pragma unroll
        for (int pp = 0; pp < 4; ++pp) {
            acc[pp] = __hfma2(d2[pp][3], A0[pp], acc[pp]);
            acc[pp] = __hfma2(d2[pp][4], C0[pp], acc[pp]);
            acc[pp] = __hfma2(d2[pp][5], B0[pp], acc[pp]);
        }
        // ky = 2 : rows rb0, rb0+1 lerped by fyb
        LOADCOLS(rb0 * RDJ, A0, C0, B0);
        LOADCOLS((rb0 + 1) * RDJ, A1, C1, B1);
        #pragma unroll
        for (int pp = 0; pp < 4; ++pp) {
            __half2 SA = lerp2(A0[pp], A1[pp], fyb2);
            __half2 SC = lerp2(C0[pp], C1[pp], fyb2);
            __half2 SB = lerp2(B0[pp], B1[pp], fyb2);
            acc[pp] = __hfma2(d2[pp][6], SA, acc[pp]);
            acc[pp] = __hfma2(d2[pp][7], SC, acc[pp]);
            acc[pp] = __hfma2(d2[pp][8], SB, acc[pp]);
        }
#undef LOADCOLS

        const size_t ob = ((size_t)n * 64 + c0) * HW_ + gi * W_ + gj;
        #pragma unroll
        for (int pp = 0; pp < 4; ++pp) {
            out[ob + (size_t)(2 * pp) * HW_]     = __low2float(acc[pp]);
            out[ob + (size_t)(2 * pp + 1) * HW_] = __high2float(acc[pp]);
        }
    }
}

extern "C" void kernel_launch(void* const* d_in, const int* in_sizes, int n_in,
                              void* d_out, int out_size, void* d_ws, size_t ws_size,
                              hipStream_t stream) {
    const float* x    = (const float*)d_in[0];
    const float* pw   = (const float*)d_in[1];
    const float* offw = (const float*)d_in[2];
    const float* offb = (const float*)d_in[3];
    const float* dwp  = (const float*)d_in[4];

    uint32_t* ypackI = (uint32_t*)d_ws;                                 // 64 MiB
    float* sbuf = (float*)((char*)d_ws + (size_t)NIMG * 8 * HW_ * 16);  // 2 MiB
    float* out  = (float*)d_out;

    hipLaunchKernelGGL(pw_off_kernel, dim3(2048), dim3(256), 0, stream,
                       x, pw, offw, offb, ypackI, sbuf);
    hipLaunchKernelGGL(deform_kernel, dim3(4, 8, NIMG * 8), dim3(512), 0, stream,
                       (const uint4*)ypackI, sbuf, dwp, out);
}